// Round 1
// baseline (711280.811 us; speedup 1.0000x reference)
//
#include <hip/hip_runtime.h>
#include <hip/hip_bf16.h>

#define H_DIM 356
#define G4 1424            // 4*H
#define NCTX 8192
#define NQ 1024
#define NTOT 9216
#define CDIM 100
#define NFILT 100
#define KW 5
#define WCH 16

typedef _Float16 half2_t __attribute__((ext_vector_type(2)));

__device__ __forceinline__ float sigmoidf_fast(float x) {
    return 1.0f / (1.0f + __expf(-x));
}
__device__ __forceinline__ float tanhf_fast(float x) {
    // 2*sigmoid(2x)-1 : safe at both extremes
    return 2.0f / (1.0f + __expf(-2.0f * x)) - 1.0f;
}
__device__ __forceinline__ unsigned pack_f16x2(float a, float b) {
    _Float16 ha = (_Float16)a, hb = (_Float16)b;
    unsigned short ua = __builtin_bit_cast(unsigned short, ha);
    unsigned short ub = __builtin_bit_cast(unsigned short, hb);
    return (unsigned)ua | ((unsigned)ub << 16);
}
__device__ __forceinline__ float fdot2f(unsigned w, unsigned h, float acc) {
#if __has_builtin(__builtin_amdgcn_fdot2)
    return __builtin_amdgcn_fdot2(__builtin_bit_cast(half2_t, w),
                                  __builtin_bit_cast(half2_t, h), acc, false);
#else
    half2_t wv = __builtin_bit_cast(half2_t, w);
    half2_t hv = __builtin_bit_cast(half2_t, h);
    return acc + (float)wv.x * (float)hv.x + (float)wv.y * (float)hv.y;
#endif
}

// ---------------------------------------------------------------------------
// Kernel 1: char-CNN + maxpool + ELMo concat + 2-layer highway.
// 16 rows per workgroup (amortizes the 2MB of highway weights across rows).
// ---------------------------------------------------------------------------
__global__ __launch_bounds__(128) void cnn_highway_kernel(
    const int* __restrict__ ctx_ids, const int* __restrict__ q_ids,
    const float* __restrict__ ctx_elmo, const float* __restrict__ q_elmo,
    const float* __restrict__ char_emb, const float* __restrict__ conv_w,
    const float* __restrict__ conv_b,
    const float* __restrict__ hw_pw, const float* __restrict__ hw_pb,
    const float* __restrict__ hw_gw, const float* __restrict__ hw_gb,
    float* __restrict__ feats_out)
{
    __shared__ float s_ce[WCH][CDIM];       // one row's char embeddings
    __shared__ float s_feats[16][H_DIM];    // 16 rows of features
    const int tid  = threadIdx.x;
    const int row0 = blockIdx.x * 16;

    // ---- conv + maxpool, one row at a time ----
    for (int rr = 0; rr < 16; ++rr) {
        const int row = row0 + rr;
        const int* ids = (row < NCTX) ? (ctx_ids + (size_t)row * WCH)
                                      : (q_ids + (size_t)(row - NCTX) * WCH);
        for (int idx = tid; idx < WCH * CDIM; idx += 128) {
            int w = idx / CDIM, c = idx - w * CDIM;
            s_ce[w][c] = char_emb[(size_t)ids[w] * CDIM + c];
        }
        __syncthreads();
        if (tid < NFILT) {
            const int f = tid;
            float s[WCH];
            float bias = conv_b[f];
            #pragma unroll
            for (int p = 0; p < WCH; ++p) s[p] = bias;
            const float* wrow = conv_w + (size_t)f * CDIM * KW;
            for (int c0 = 0; c0 < CDIM; c0 += 4) {
                float wv[20];
                const float4* wp4 = (const float4*)(wrow + c0 * KW);
                #pragma unroll
                for (int u = 0; u < 5; ++u) {
                    float4 v = wp4[u];
                    wv[u * 4 + 0] = v.x; wv[u * 4 + 1] = v.y;
                    wv[u * 4 + 2] = v.z; wv[u * 4 + 3] = v.w;
                }
                #pragma unroll
                for (int cc = 0; cc < 4; ++cc) {
                    float ce[WCH];
                    #pragma unroll
                    for (int w = 0; w < WCH; ++w) ce[w] = s_ce[w][c0 + cc];
                    #pragma unroll
                    for (int p = 0; p < WCH; ++p) {
                        #pragma unroll
                        for (int k = 0; k < KW; ++k) {
                            const int wpos = p + k - 2;
                            if (wpos >= 0 && wpos < WCH)
                                s[p] = fmaf(ce[wpos], wv[cc * 5 + k], s[p]);
                        }
                    }
                }
            }
            float m = s[0];
            #pragma unroll
            for (int p = 1; p < WCH; ++p) m = fmaxf(m, s[p]);
            s_feats[rr][f] = m;
        }
        __syncthreads();
    }

    // ---- ELMo part of the features ----
    for (int idx = tid; idx < 16 * 256; idx += 128) {
        int rr = idx >> 8, c = idx & 255;
        int row = row0 + rr;
        float v = (row < NCTX) ? ctx_elmo[(size_t)row * 256 + c]
                               : q_elmo[(size_t)(row - NCTX) * 256 + c];
        s_feats[rr][CDIM + c] = v;
    }
    __syncthreads();

    // ---- highway (2 layers) ----
    for (int l = 0; l < 2; ++l) {
        float newv[3][16];
        for (int it = 0; it < 3; ++it) {
            const int j = it * 128 + tid;
            if (j < H_DIM) {
                float accP[16], accG[16];
                #pragma unroll
                for (int r = 0; r < 16; ++r) { accP[r] = 0.0f; accG[r] = 0.0f; }
                const float* pw = hw_pw + ((size_t)l * H_DIM + j) * H_DIM;
                const float* gw = hw_gw + ((size_t)l * H_DIM + j) * H_DIM;
                for (int k0 = 0; k0 < H_DIM; k0 += 4) {
                    float4 wpv4 = *(const float4*)(pw + k0);
                    float4 wgv4 = *(const float4*)(gw + k0);
                    float wp[4] = {wpv4.x, wpv4.y, wpv4.z, wpv4.w};
                    float wg[4] = {wgv4.x, wgv4.y, wgv4.z, wgv4.w};
                    #pragma unroll
                    for (int kk = 0; kk < 4; ++kk) {
                        #pragma unroll
                        for (int r = 0; r < 16; ++r) {
                            float fv = s_feats[r][k0 + kk];
                            accP[r] = fmaf(fv, wp[kk], accP[r]);
                            accG[r] = fmaf(fv, wg[kk], accG[r]);
                        }
                    }
                }
                const float pb = hw_pb[l * H_DIM + j];
                const float gb = hw_gb[l * H_DIM + j];
                #pragma unroll
                for (int r = 0; r < 16; ++r) {
                    float p = accP[r] + pb; p = p > 0.0f ? p : 0.0f;
                    float g = sigmoidf_fast(accG[r] + gb);
                    newv[it][r] = g * p + (1.0f - g) * s_feats[r][j];
                }
            }
        }
        __syncthreads();
        for (int it = 0; it < 3; ++it) {
            const int j = it * 128 + tid;
            if (j < H_DIM) {
                #pragma unroll
                for (int r = 0; r < 16; ++r) s_feats[r][j] = newv[it][r];
            }
        }
        __syncthreads();
    }

    for (int idx = tid; idx < 16 * H_DIM; idx += 128) {
        int rr = idx / H_DIM, j = idx - rr * H_DIM;
        feats_out[(size_t)(row0 + rr) * H_DIM + j] = s_feats[rr][j];
    }
}

// ---------------------------------------------------------------------------
// Kernel 2: C[z][m][n] = A[m][:] . B[z][n][:] + (bia[z][n] + bib[z][n])
// f32, 64x64 tile, 256 threads, 4x4 micro-tile. K in {356, 712} (K%4==0).
// ---------------------------------------------------------------------------
__global__ __launch_bounds__(256) void gemm_nt_bias_kernel(
    const float* __restrict__ A, const float* __restrict__ B,
    const float* __restrict__ bia, const float* __restrict__ bib,
    float* __restrict__ C, int M, int N, int K)
{
    const int z = blockIdx.z;
    const float* Bz = B + (size_t)z * N * K;
    float* Cz = C + (size_t)z * M * N;
    const int n0 = blockIdx.x * 64;
    const int m0 = blockIdx.y * 64;
    __shared__ float As[64][17];
    __shared__ float Bs[64][17];
    const int tid = threadIdx.x;
    const int tx = tid & 15, ty = tid >> 4;
    const int lr = tid >> 2;          // 0..63
    const int lc = (tid & 3) * 4;     // 0,4,8,12
    float acc[4][4];
    #pragma unroll
    for (int i = 0; i < 4; ++i)
        #pragma unroll
        for (int j = 0; j < 4; ++j) acc[i][j] = 0.0f;

    const int ktiles = (K + 15) / 16;
    for (int kt = 0; kt < ktiles; ++kt) {
        const int k0 = kt * 16;
        float4 av = {0, 0, 0, 0}, bv = {0, 0, 0, 0};
        if (k0 + lc < K)      // K%4==0 -> float4 fully valid or fully invalid
            av = *(const float4*)(A + (size_t)(m0 + lr) * K + k0 + lc);
        const int bn = n0 + lr;
        if (bn < N && k0 + lc < K)
            bv = *(const float4*)(Bz + (size_t)bn * K + k0 + lc);
        __syncthreads();
        As[lr][lc + 0] = av.x; As[lr][lc + 1] = av.y;
        As[lr][lc + 2] = av.z; As[lr][lc + 3] = av.w;
        Bs[lr][lc + 0] = bv.x; Bs[lr][lc + 1] = bv.y;
        Bs[lr][lc + 2] = bv.z; Bs[lr][lc + 3] = bv.w;
        __syncthreads();
        #pragma unroll
        for (int kk = 0; kk < 16; ++kk) {
            float a[4], b[4];
            #pragma unroll
            for (int i = 0; i < 4; ++i) a[i] = As[ty * 4 + i][kk];
            #pragma unroll
            for (int j = 0; j < 4; ++j) b[j] = Bs[tx * 4 + j][kk];
            #pragma unroll
            for (int i = 0; i < 4; ++i)
                #pragma unroll
                for (int j = 0; j < 4; ++j)
                    acc[i][j] = fmaf(a[i], b[j], acc[i][j]);
        }
    }
    #pragma unroll
    for (int j = 0; j < 4; ++j) {
        const int n = n0 + tx * 4 + j;
        if (n < N) {
            const float bsum = bia[(size_t)z * N + n] + bib[(size_t)z * N + n];
            #pragma unroll
            for (int i = 0; i < 4; ++i) {
                const int m = m0 + ty * 4 + i;
                Cz[(size_t)m * N + n] = acc[i][j] + bsum;
            }
        }
    }
}

// ---------------------------------------------------------------------------
// Kernel 3: persistent LSTM scan. grid = 4: (doc, dir). 1024 threads.
// W_hh held f16-packed in VGPRs (thread t owns rows t and 1024+t (t<400)).
// h broadcast via LDS f16 pairs; c-state f32 in registers of threads <356.
// ---------------------------------------------------------------------------
__global__ __launch_bounds__(1024, 1) void lstm_scan_kernel(
    const float* __restrict__ xg,    // [2][9216][1424] (biases folded in)
    const float* __restrict__ whh,   // [2][1424][356]
    const float* __restrict__ h0,    // [2][356] (layer-sliced)
    const float* __restrict__ c0,    // [2][356]
    float* __restrict__ out)         // [9216][712]
{
    const int blk = blockIdx.x;
    const int doc = blk >> 1, dir = blk & 1;
    const int T = doc ? NQ : NCTX;
    const int rbase = doc ? NCTX : 0;
    const int tid = threadIdx.x;
    const bool two = (tid < G4 - 1024);   // 400 threads own a second row

    __shared__ unsigned s_h[192];   // f16x2 pairs of h; [178..191] stay zero
    __shared__ float s_g[G4];

    // ---- stage weights into registers (f16 pairs) ----
    unsigned w0[180], w1[180];
    {
        const float4* wr4 = (const float4*)(whh + ((size_t)dir * G4 + tid) * H_DIM);
        #pragma unroll
        for (int u = 0; u < 89; ++u) {
            float4 v = wr4[u];
            w0[2 * u]     = pack_f16x2(v.x, v.y);
            w0[2 * u + 1] = pack_f16x2(v.z, v.w);
        }
        w0[178] = 0u; w0[179] = 0u;
        if (two) {
            const float4* w14 =
                (const float4*)(whh + ((size_t)dir * G4 + 1024 + tid) * H_DIM);
            #pragma unroll
            for (int u = 0; u < 89; ++u) {
                float4 v = w14[u];
                w1[2 * u]     = pack_f16x2(v.x, v.y);
                w1[2 * u + 1] = pack_f16x2(v.z, v.w);
            }
            w1[178] = 0u; w1[179] = 0u;
        }
    }

    // ---- init states ----
    float c_state = 0.0f;
    if (tid < H_DIM) c_state = c0[dir * H_DIM + tid];
    if (tid < 192) {
        const int j0 = 2 * tid, j1 = 2 * tid + 1;
        float a = (j0 < H_DIM) ? h0[dir * H_DIM + j0] : 0.0f;
        float b = (j1 < H_DIM) ? h0[dir * H_DIM + j1] : 0.0f;
        s_h[tid] = pack_f16x2(a, b);
    }
    const float* xgd = xg + (size_t)dir * NTOT * G4;
    __syncthreads();

    for (int t = 0; t < T; ++t) {
        const int row = rbase + (dir == 0 ? t : (T - 1 - t));
        const float* xr = xgd + (size_t)row * G4;
        const float xv0 = xr[tid];
        const float xv1 = two ? xr[1024 + tid] : 0.0f;
        float a0 = 0, a1 = 0, a2 = 0, a3 = 0;
        float b0 = 0, b1 = 0, b2 = 0, b3 = 0;
        const uint4* hp = (const uint4*)s_h;
        #pragma unroll
        for (int q = 0; q < 45; ++q) {
            uint4 hv = hp[q];
            a0 = fdot2f(w0[4 * q + 0], hv.x, a0);
            a1 = fdot2f(w0[4 * q + 1], hv.y, a1);
            a2 = fdot2f(w0[4 * q + 2], hv.z, a2);
            a3 = fdot2f(w0[4 * q + 3], hv.w, a3);
            if (two) {
                b0 = fdot2f(w1[4 * q + 0], hv.x, b0);
                b1 = fdot2f(w1[4 * q + 1], hv.y, b1);
                b2 = fdot2f(w1[4 * q + 2], hv.z, b2);
                b3 = fdot2f(w1[4 * q + 3], hv.w, b3);
            }
        }
        s_g[tid] = xv0 + ((a0 + a1) + (a2 + a3));
        if (two) s_g[1024 + tid] = xv1 + ((b0 + b1) + (b2 + b3));
        __syncthreads();
        if (tid < H_DIM) {
            const float gi = s_g[tid];
            const float gf = s_g[tid + H_DIM];
            const float gg = s_g[tid + 2 * H_DIM];
            const float go = s_g[tid + 3 * H_DIM];
            const float ii = sigmoidf_fast(gi);
            const float ff = sigmoidf_fast(gf);
            const float g  = tanhf_fast(gg);
            const float oo = sigmoidf_fast(go);
            c_state = ff * c_state + ii * g;
            const float hh = oo * tanhf_fast(c_state);
            out[(size_t)row * 712 + dir * H_DIM + tid] = hh;
            _Float16 hf = (_Float16)hh;
            ((unsigned short*)s_h)[tid] = __builtin_bit_cast(unsigned short, hf);
        }
        __syncthreads();
    }
}

// ---------------------------------------------------------------------------
extern "C" void kernel_launch(void* const* d_in, const int* in_sizes, int n_in,
                              void* d_out, int out_size, void* d_ws, size_t ws_size,
                              hipStream_t stream) {
    (void)in_sizes; (void)n_in; (void)out_size; (void)ws_size;
    const int*   ctx_ids  = (const int*)d_in[0];
    const int*   q_ids    = (const int*)d_in[1];
    const float* ctx_elmo = (const float*)d_in[2];
    const float* q_elmo   = (const float*)d_in[3];
    const float* char_emb = (const float*)d_in[4];
    const float* conv_w   = (const float*)d_in[5];
    const float* conv_b   = (const float*)d_in[6];
    const float* hw_pw    = (const float*)d_in[7];
    const float* hw_pb    = (const float*)d_in[8];
    const float* hw_gw    = (const float*)d_in[9];
    const float* hw_gb    = (const float*)d_in[10];
    const float* w_ih0    = (const float*)d_in[11];
    const float* w_hh0    = (const float*)d_in[12];
    const float* b_ih0    = (const float*)d_in[13];
    const float* b_hh0    = (const float*)d_in[14];
    const float* w_ih1    = (const float*)d_in[15];
    const float* w_hh1    = (const float*)d_in[16];
    const float* b_ih1    = (const float*)d_in[17];
    const float* b_hh1    = (const float*)d_in[18];
    const float* h0       = (const float*)d_in[19];
    const float* c0       = (const float*)d_in[20];
    float* out = (float*)d_out;
    float* ws  = (float*)d_ws;

    float* xg    = ws;                                   // 2*9216*1424 f32
    float* feats = xg + (size_t)2 * NTOT * G4;           // 9216*356
    float* l1out = feats + (size_t)NTOT * H_DIM;         // 9216*712
    // total ws use: 36,083,712 f32 = 144.3 MB

    cnn_highway_kernel<<<NTOT / 16, 128, 0, stream>>>(
        ctx_ids, q_ids, ctx_elmo, q_elmo, char_emb, conv_w, conv_b,
        hw_pw, hw_pb, hw_gw, hw_gb, feats);

    dim3 ggrid((G4 + 63) / 64, NTOT / 64, 2);
    gemm_nt_bias_kernel<<<ggrid, 256, 0, stream>>>(
        feats, w_ih0, b_ih0, b_hh0, xg, NTOT, G4, H_DIM);

    lstm_scan_kernel<<<4, 1024, 0, stream>>>(xg, w_hh0, h0, c0, l1out);

    gemm_nt_bias_kernel<<<ggrid, 256, 0, stream>>>(
        l1out, w_ih1, b_ih1, b_hh1, xg, NTOT, G4, 2 * H_DIM);

    lstm_scan_kernel<<<4, 1024, 0, stream>>>(
        xg, w_hh1, h0 + 2 * H_DIM, c0 + 2 * H_DIM, out);
}

// Round 2
// 46028.641 us; speedup vs baseline: 15.4530x; 15.4530x over previous
//
#include <hip/hip_runtime.h>
#include <hip/hip_bf16.h>

#define H_DIM 356
#define G4 1424            // 4*H
#define NCTX 8192
#define NQ 1024
#define NTOT 9216
#define CDIM 100
#define NFILT 100
#define KW 5
#define WCH 16

typedef _Float16 f16_t;
typedef _Float16 half2_t __attribute__((ext_vector_type(2)));

__device__ __forceinline__ float sigmoidf_fast(float x) {
    return 1.0f / (1.0f + __expf(-x));
}
__device__ __forceinline__ float tanhf_fast(float x) {
    return 2.0f / (1.0f + __expf(-2.0f * x)) - 1.0f;
}
__device__ __forceinline__ unsigned pack_f16x2(float a, float b) {
    _Float16 ha = (_Float16)a, hb = (_Float16)b;
    unsigned short ua = __builtin_bit_cast(unsigned short, ha);
    unsigned short ub = __builtin_bit_cast(unsigned short, hb);
    return (unsigned)ua | ((unsigned)ub << 16);
}
__device__ __forceinline__ float fdot2f(unsigned w, unsigned h, float acc) {
#if __has_builtin(__builtin_amdgcn_fdot2)
    return __builtin_amdgcn_fdot2(__builtin_bit_cast(half2_t, w),
                                  __builtin_bit_cast(half2_t, h), acc, false);
#else
    half2_t wv = __builtin_bit_cast(half2_t, w);
    half2_t hv = __builtin_bit_cast(half2_t, h);
    return acc + (float)wv.x * (float)hv.x + (float)wv.y * (float)hv.y;
#endif
}

// ---------------------------------------------------------------------------
// Kernel 1: char-CNN + maxpool + ELMo concat + 2-layer highway. (unchanged)
// ---------------------------------------------------------------------------
__global__ __launch_bounds__(128) void cnn_highway_kernel(
    const int* __restrict__ ctx_ids, const int* __restrict__ q_ids,
    const float* __restrict__ ctx_elmo, const float* __restrict__ q_elmo,
    const float* __restrict__ char_emb, const float* __restrict__ conv_w,
    const float* __restrict__ conv_b,
    const float* __restrict__ hw_pw, const float* __restrict__ hw_pb,
    const float* __restrict__ hw_gw, const float* __restrict__ hw_gb,
    float* __restrict__ feats_out)
{
    __shared__ float s_ce[WCH][CDIM];
    __shared__ float s_feats[16][H_DIM];
    const int tid  = threadIdx.x;
    const int row0 = blockIdx.x * 16;

    for (int rr = 0; rr < 16; ++rr) {
        const int row = row0 + rr;
        const int* ids = (row < NCTX) ? (ctx_ids + (size_t)row * WCH)
                                      : (q_ids + (size_t)(row - NCTX) * WCH);
        for (int idx = tid; idx < WCH * CDIM; idx += 128) {
            int w = idx / CDIM, c = idx - w * CDIM;
            s_ce[w][c] = char_emb[(size_t)ids[w] * CDIM + c];
        }
        __syncthreads();
        if (tid < NFILT) {
            const int f = tid;
            float s[WCH];
            float bias = conv_b[f];
            #pragma unroll
            for (int p = 0; p < WCH; ++p) s[p] = bias;
            const float* wrow = conv_w + (size_t)f * CDIM * KW;
            for (int c0 = 0; c0 < CDIM; c0 += 4) {
                float wv[20];
                const float4* wp4 = (const float4*)(wrow + c0 * KW);
                #pragma unroll
                for (int u = 0; u < 5; ++u) {
                    float4 v = wp4[u];
                    wv[u * 4 + 0] = v.x; wv[u * 4 + 1] = v.y;
                    wv[u * 4 + 2] = v.z; wv[u * 4 + 3] = v.w;
                }
                #pragma unroll
                for (int cc = 0; cc < 4; ++cc) {
                    float ce[WCH];
                    #pragma unroll
                    for (int w = 0; w < WCH; ++w) ce[w] = s_ce[w][c0 + cc];
                    #pragma unroll
                    for (int p = 0; p < WCH; ++p) {
                        #pragma unroll
                        for (int k = 0; k < KW; ++k) {
                            const int wpos = p + k - 2;
                            if (wpos >= 0 && wpos < WCH)
                                s[p] = fmaf(ce[wpos], wv[cc * 5 + k], s[p]);
                        }
                    }
                }
            }
            float m = s[0];
            #pragma unroll
            for (int p = 1; p < WCH; ++p) m = fmaxf(m, s[p]);
            s_feats[rr][f] = m;
        }
        __syncthreads();
    }

    for (int idx = tid; idx < 16 * 256; idx += 128) {
        int rr = idx >> 8, c = idx & 255;
        int row = row0 + rr;
        float v = (row < NCTX) ? ctx_elmo[(size_t)row * 256 + c]
                               : q_elmo[(size_t)(row - NCTX) * 256 + c];
        s_feats[rr][CDIM + c] = v;
    }
    __syncthreads();

    for (int l = 0; l < 2; ++l) {
        float newv[3][16];
        for (int it = 0; it < 3; ++it) {
            const int j = it * 128 + tid;
            if (j < H_DIM) {
                float accP[16], accG[16];
                #pragma unroll
                for (int r = 0; r < 16; ++r) { accP[r] = 0.0f; accG[r] = 0.0f; }
                const float* pw = hw_pw + ((size_t)l * H_DIM + j) * H_DIM;
                const float* gw = hw_gw + ((size_t)l * H_DIM + j) * H_DIM;
                for (int k0 = 0; k0 < H_DIM; k0 += 4) {
                    float4 wpv4 = *(const float4*)(pw + k0);
                    float4 wgv4 = *(const float4*)(gw + k0);
                    float wp[4] = {wpv4.x, wpv4.y, wpv4.z, wpv4.w};
                    float wg[4] = {wgv4.x, wgv4.y, wgv4.z, wgv4.w};
                    #pragma unroll
                    for (int kk = 0; kk < 4; ++kk) {
                        #pragma unroll
                        for (int r = 0; r < 16; ++r) {
                            float fv = s_feats[r][k0 + kk];
                            accP[r] = fmaf(fv, wp[kk], accP[r]);
                            accG[r] = fmaf(fv, wg[kk], accG[r]);
                        }
                    }
                }
                const float pb = hw_pb[l * H_DIM + j];
                const float gb = hw_gb[l * H_DIM + j];
                #pragma unroll
                for (int r = 0; r < 16; ++r) {
                    float p = accP[r] + pb; p = p > 0.0f ? p : 0.0f;
                    float g = sigmoidf_fast(accG[r] + gb);
                    newv[it][r] = g * p + (1.0f - g) * s_feats[r][j];
                }
            }
        }
        __syncthreads();
        for (int it = 0; it < 3; ++it) {
            const int j = it * 128 + tid;
            if (j < H_DIM) {
                #pragma unroll
                for (int r = 0; r < 16; ++r) s_feats[r][j] = newv[it][r];
            }
        }
        __syncthreads();
    }

    for (int idx = tid; idx < 16 * H_DIM; idx += 128) {
        int rr = idx / H_DIM, j = idx - rr * H_DIM;
        feats_out[(size_t)(row0 + rr) * H_DIM + j] = s_feats[rr][j];
    }
}

// ---------------------------------------------------------------------------
// Kernel 2: C[z][m][n] = A[m][:] . B[z][n][:] + bias, f16 output.
// ---------------------------------------------------------------------------
__global__ __launch_bounds__(256) void gemm_nt_bias_kernel(
    const float* __restrict__ A, const float* __restrict__ B,
    const float* __restrict__ bia, const float* __restrict__ bib,
    f16_t* __restrict__ C, int M, int N, int K)
{
    const int z = blockIdx.z;
    const float* Bz = B + (size_t)z * N * K;
    f16_t* Cz = C + (size_t)z * M * N;
    const int n0 = blockIdx.x * 64;
    const int m0 = blockIdx.y * 64;
    __shared__ float As[64][17];
    __shared__ float Bs[64][17];
    const int tid = threadIdx.x;
    const int tx = tid & 15, ty = tid >> 4;
    const int lr = tid >> 2;
    const int lc = (tid & 3) * 4;
    float acc[4][4];
    #pragma unroll
    for (int i = 0; i < 4; ++i)
        #pragma unroll
        for (int j = 0; j < 4; ++j) acc[i][j] = 0.0f;

    const int ktiles = (K + 15) / 16;
    for (int kt = 0; kt < ktiles; ++kt) {
        const int k0 = kt * 16;
        float4 av = {0, 0, 0, 0}, bv = {0, 0, 0, 0};
        if (k0 + lc < K)
            av = *(const float4*)(A + (size_t)(m0 + lr) * K + k0 + lc);
        const int bn = n0 + lr;
        if (bn < N && k0 + lc < K)
            bv = *(const float4*)(Bz + (size_t)bn * K + k0 + lc);
        __syncthreads();
        As[lr][lc + 0] = av.x; As[lr][lc + 1] = av.y;
        As[lr][lc + 2] = av.z; As[lr][lc + 3] = av.w;
        Bs[lr][lc + 0] = bv.x; Bs[lr][lc + 1] = bv.y;
        Bs[lr][lc + 2] = bv.z; Bs[lr][lc + 3] = bv.w;
        __syncthreads();
        #pragma unroll
        for (int kk = 0; kk < 16; ++kk) {
            float a[4], b[4];
            #pragma unroll
            for (int i = 0; i < 4; ++i) a[i] = As[ty * 4 + i][kk];
            #pragma unroll
            for (int j = 0; j < 4; ++j) b[j] = Bs[tx * 4 + j][kk];
            #pragma unroll
            for (int i = 0; i < 4; ++i)
                #pragma unroll
                for (int j = 0; j < 4; ++j)
                    acc[i][j] = fmaf(a[i], b[j], acc[i][j]);
        }
    }
    #pragma unroll
    for (int j = 0; j < 4; ++j) {
        const int n = n0 + tx * 4 + j;
        if (n < N) {
            const float bsum = bia[(size_t)z * N + n] + bib[(size_t)z * N + n];
            #pragma unroll
            for (int i = 0; i < 4; ++i) {
                const int m = m0 + ty * 4 + i;
                Cz[(size_t)m * N + n] = (f16_t)(acc[i][j] + bsum);
            }
        }
    }
}

// ---------------------------------------------------------------------------
// Kernel 3: LSTM scan, 4 blocks per scan (16 active blocks), 512 threads.
// Block `sub` of scan (doc,dir) owns h indices [sub*89, sub*89+89).
// Thread t<356 holds one full W_hh row (178 f16x2 VGPRs): row g*356+s0+j,
// t = g*89+j. h exchanged per step via device-scope atomics + flags.
// Grid of 32: scan = bid&7 (co-locates a scan's 4 blocks on one XCD per the
// bid%8 dispatch heuristic — perf only, correctness from agent-scope atomics).
// ---------------------------------------------------------------------------
__global__ __launch_bounds__(512, 2) void lstm_scan4_kernel(
    const f16_t* __restrict__ xg,    // [2][9216][1424] f16, biases folded
    const float* __restrict__ whh,   // [2][1424][356] f32
    const float* __restrict__ h0,    // [2][356]
    const float* __restrict__ c0,    // [2][356]
    float* __restrict__ out,         // [9216][712]
    float* hbuf,                     // per-scan state history [sum(T+1)][356]
    int* flags)                      // per-scan [T+1][4]
{
    const int bid = blockIdx.x;
    const int s = bid & 7;
    if (s >= 4) return;
    const int sub = bid >> 3;
    const int doc = s >> 1, dir = s & 1;
    const int T = doc ? NQ : NCTX;
    const int rbase = doc ? NCTX : 0;
    const int soff = (s == 0) ? 0 : (s == 1) ? 8193 : (s == 2) ? 16386 : 17411;
    float* hb = hbuf + (size_t)soff * H_DIM;
    int* fl = flags + (size_t)soff * 4;
    const int s0 = sub * 89;
    const int tid = threadIdx.x;

    __shared__ __align__(16) unsigned s_h[180];
    __shared__ float s_g[356];

    const int g = tid / 89, j = tid - g * 89;      // valid for tid<356
    const int rg = g * H_DIM + s0 + j;             // gate row within dir

    // ---- stage one full W_hh row into registers (f16 pairs) ----
    unsigned w[180];
    if (tid < 356) {
        const float4* wr = (const float4*)(whh + ((size_t)dir * G4 + rg) * H_DIM);
        #pragma unroll
        for (int u = 0; u < 89; ++u) {
            float4 v = wr[u];
            w[2 * u]     = pack_f16x2(v.x, v.y);
            w[2 * u + 1] = pack_f16x2(v.z, v.w);
        }
        w[178] = 0u; w[179] = 0u;
    }
    if (tid == 400) { s_h[178] = 0u; s_h[179] = 0u; }

    // ---- init state: write own slice of hbuf[0], set flag ----
    float c_state = 0.0f;
    if (tid < 89) {
        c_state = c0[dir * H_DIM + s0 + tid];
        float hv = h0[dir * H_DIM + s0 + tid];
        __hip_atomic_store(&hb[s0 + tid], hv, __ATOMIC_RELAXED,
                           __HIP_MEMORY_SCOPE_AGENT);
    }
    __syncthreads();   // drains the stores (vmcnt0 before s_barrier)
    if (tid == 0)
        __hip_atomic_store(&fl[sub], 1, __ATOMIC_RELEASE,
                           __HIP_MEMORY_SCOPE_AGENT);

    const f16_t* xgd = xg + (size_t)dir * NTOT * G4;
    int row = rbase + (dir ? (T - 1) : 0);
    float xv = 0.0f;
    if (tid < 356) xv = (float)xgd[(size_t)row * G4 + rg];

    for (int t = 0; t < T; ++t) {
        // prefetch next step's xg value (covered by the exchange latency)
        float xv_next = 0.0f;
        const int row_next = rbase + (dir ? (T - 2 - t) : (t + 1));
        if (t + 1 < T && tid < 356)
            xv_next = (float)xgd[(size_t)row_next * G4 + rg];

        // wait for all 4 slices of h[t]
        if (tid < 4) {
            while (__hip_atomic_load(&fl[t * 4 + tid], __ATOMIC_ACQUIRE,
                                     __HIP_MEMORY_SCOPE_AGENT) == 0)
                __builtin_amdgcn_s_sleep(1);
        }
        __syncthreads();

        // load h[t] (bypass L1 via relaxed agent atomics), pack f16x2 to LDS
        if (tid < 178) {
            float a = __hip_atomic_load(&hb[(size_t)t * H_DIM + 2 * tid],
                                        __ATOMIC_RELAXED, __HIP_MEMORY_SCOPE_AGENT);
            float b = __hip_atomic_load(&hb[(size_t)t * H_DIM + 2 * tid + 1],
                                        __ATOMIC_RELAXED, __HIP_MEMORY_SCOPE_AGENT);
            s_h[tid] = pack_f16x2(a, b);
        }
        __syncthreads();

        // dot: full row per thread, acc seeded with xg
        if (tid < 356) {
            float a0 = xv, a1 = 0.0f, a2 = 0.0f, a3 = 0.0f;
            const uint4* hp = (const uint4*)s_h;
            #pragma unroll
            for (int q = 0; q < 45; ++q) {
                uint4 hv = hp[q];
                a0 = fdot2f(w[4 * q + 0], hv.x, a0);
                a1 = fdot2f(w[4 * q + 1], hv.y, a1);
                a2 = fdot2f(w[4 * q + 2], hv.z, a2);
                a3 = fdot2f(w[4 * q + 3], hv.w, a3);
            }
            s_g[tid] = (a0 + a1) + (a2 + a3);
        }
        __syncthreads();

        // activation + state update for the 89 owned h indices
        if (tid < 89) {
            const float gi = s_g[tid];
            const float gf = s_g[89 + tid];
            const float gg = s_g[178 + tid];
            const float go = s_g[267 + tid];
            const float ii = sigmoidf_fast(gi);
            const float ff = sigmoidf_fast(gf);
            const float gt = tanhf_fast(gg);
            const float oo = sigmoidf_fast(go);
            c_state = ff * c_state + ii * gt;
            const float hh = oo * tanhf_fast(c_state);
            out[(size_t)row * 712 + dir * H_DIM + s0 + tid] = hh;
            __hip_atomic_store(&hb[(size_t)(t + 1) * H_DIM + s0 + tid], hh,
                               __ATOMIC_RELAXED, __HIP_MEMORY_SCOPE_AGENT);
        }
        __syncthreads();   // drain stores before publishing
        if (tid == 0)
            __hip_atomic_store(&fl[(t + 1) * 4 + sub], 1, __ATOMIC_RELEASE,
                               __HIP_MEMORY_SCOPE_AGENT);
        xv = xv_next;
        row = row_next;
    }
}

// ---------------------------------------------------------------------------
extern "C" void kernel_launch(void* const* d_in, const int* in_sizes, int n_in,
                              void* d_out, int out_size, void* d_ws, size_t ws_size,
                              hipStream_t stream) {
    (void)in_sizes; (void)n_in; (void)out_size; (void)ws_size;
    const int*   ctx_ids  = (const int*)d_in[0];
    const int*   q_ids    = (const int*)d_in[1];
    const float* ctx_elmo = (const float*)d_in[2];
    const float* q_elmo   = (const float*)d_in[3];
    const float* char_emb = (const float*)d_in[4];
    const float* conv_w   = (const float*)d_in[5];
    const float* conv_b   = (const float*)d_in[6];
    const float* hw_pw    = (const float*)d_in[7];
    const float* hw_pb    = (const float*)d_in[8];
    const float* hw_gw    = (const float*)d_in[9];
    const float* hw_gb    = (const float*)d_in[10];
    const float* w_ih0    = (const float*)d_in[11];
    const float* w_hh0    = (const float*)d_in[12];
    const float* b_ih0    = (const float*)d_in[13];
    const float* b_hh0    = (const float*)d_in[14];
    const float* w_ih1    = (const float*)d_in[15];
    const float* w_hh1    = (const float*)d_in[16];
    const float* b_ih1    = (const float*)d_in[17];
    const float* b_hh1    = (const float*)d_in[18];
    const float* h0       = (const float*)d_in[19];
    const float* c0       = (const float*)d_in[20];
    float* out = (float*)d_out;

    // ws layout (bytes): xg f16 52.5MB | feats f32 13.1MB | l1out f32 26.2MB
    //                  | hbuf f32 26.3MB | flags 0.6MB   -> total ~118.6MB
    f16_t* xg    = (f16_t*)d_ws;
    float* feats = (float*)((char*)d_ws + (size_t)2 * NTOT * G4 * sizeof(f16_t));
    float* l1out = feats + (size_t)NTOT * H_DIM;
    float* hbuf  = l1out + (size_t)NTOT * 712;
    int*   flags = (int*)(hbuf + (size_t)18436 * H_DIM);   // 2*8193+2*1025 states
    int*   flags1 = flags + 73744;

    hipMemsetAsync(flags, 0, (size_t)2 * 73744 * sizeof(int), stream);

    cnn_highway_kernel<<<NTOT / 16, 128, 0, stream>>>(
        ctx_ids, q_ids, ctx_elmo, q_elmo, char_emb, conv_w, conv_b,
        hw_pw, hw_pb, hw_gw, hw_gb, feats);

    dim3 ggrid((G4 + 63) / 64, NTOT / 64, 2);
    gemm_nt_bias_kernel<<<ggrid, 256, 0, stream>>>(
        feats, w_ih0, b_ih0, b_hh0, xg, NTOT, G4, H_DIM);

    lstm_scan4_kernel<<<32, 512, 0, stream>>>(
        xg, w_hh0, h0, c0, l1out, hbuf, flags);

    gemm_nt_bias_kernel<<<ggrid, 256, 0, stream>>>(
        l1out, w_ih1, b_ih1, b_hh1, xg, NTOT, G4, 2 * H_DIM);

    lstm_scan4_kernel<<<32, 512, 0, stream>>>(
        xg, w_hh1, h0 + 2 * H_DIM, c0 + 2 * H_DIM, out, hbuf, flags1);
}